// Round 13
// baseline (1275.258 us; speedup 1.0000x reference)
//
#include <hip/hip_runtime.h>
#include <stdint.h>
#include <stddef.h>

// ---------------------------------------------------------------------------
// CounterfactualDiffusion: 50 sequential steps of 4-layer MLP (258->512->512
// ->512->128) + DDPM update with JAX partitionable-threefry noise, batch 8192.
// Persistent kernel: 256 WGs x 1024 threads (16 waves), each WG owns 32 rows.
// R6/R11/R15 (985us, clean): transposed dataflow (W = MFMA A-operand, h^T=B).
// R17 (969.5us): persist w4 ks0-7 in LDS once -> -128KB/CU/step L2 stream.
// Measured stream sensitivity: ~0.125us per KB/step removed (stream on the
// critical path at ~50% utilization). Mechanism = cross-step PERSISTENCE:
// any weight byte in LDS saves its per-step L2 traffic x50 steps; w4 bytes
// are worth 2x/step (read by both ntile wave-groups).
// Ruled out this session: register prefetch (64/128-reg wall, 7 spills),
// TLP (R12), VALU count (R15: zero), bank conflicts (2-way writes, free),
// 2 WGs/CU (R16: doubles stream), full unroll (R14: spills).
// R18 (this round): maximize the one working lever — W4LKS 8 -> 10
// (+16KB LDS -> 153.5KB, removes another 32KB/CU/step). This fills LDS;
// the persist mechanism is exhausted after this round.
// Tripwires: WRITE ~6MB, VGPR 64, LDS_Block_Size ~157184.
// ---------------------------------------------------------------------------

typedef __bf16 bf16;
typedef __bf16 bf16x4 __attribute__((ext_vector_type(4)));
typedef __bf16 bf16x8 __attribute__((ext_vector_type(8)));
typedef float  floatx4 __attribute__((ext_vector_type(4)));

#define NSTEPS    50
#define WG_ROWS   32
#define XB_STRIDE 136   // 128 + 8 pad
#define H_STRIDE  520   // 512 + 8 pad
#define W4LKS     10    // w4 K-steps persisted in LDS (of 16)

__device__ __forceinline__ uint32_t rotl32(uint32_t x, int r) {
  return (x << r) | (x >> (32 - r));
}

// JAX threefry-2x32, 20 rounds.
__device__ __forceinline__ void threefry2x32(uint32_t k0, uint32_t k1,
                                             uint32_t x0, uint32_t x1,
                                             uint32_t& o0, uint32_t& o1) {
  uint32_t k2 = k0 ^ k1 ^ 0x1BD11BDAu;
  x0 += k0; x1 += k1;
#define TF_R(R) { x0 += x1; x1 = rotl32(x1, R); x1 ^= x0; }
  TF_R(13) TF_R(15) TF_R(26) TF_R(6)
  x0 += k1; x1 += k2 + 1u;
  TF_R(17) TF_R(29) TF_R(16) TF_R(24)
  x0 += k2; x1 += k0 + 2u;
  TF_R(13) TF_R(15) TF_R(26) TF_R(6)
  x0 += k0; x1 += k1 + 3u;
  TF_R(17) TF_R(29) TF_R(16) TF_R(24)
  x0 += k1; x1 += k2 + 4u;
  TF_R(13) TF_R(15) TF_R(26) TF_R(6)
  x0 += k2; x1 += k0 + 5u;
#undef TF_R
  o0 = x0; o1 = x1;
}

// XLA's ErfInv32 (Giles), branchless select: both polys computed, vcc select.
__device__ __forceinline__ float erfinv_xla_bl(float x) {
  float w = -0.6931471805599453f * __builtin_amdgcn_logf(fmaf(-x, x, 1.0f));
  float wa = w - 2.5f;
  float pa = 2.81022636e-08f;
  pa = fmaf(pa, wa, 3.43273939e-07f);
  pa = fmaf(pa, wa, -3.5233877e-06f);
  pa = fmaf(pa, wa, -4.39150654e-06f);
  pa = fmaf(pa, wa, 0.00021858087f);
  pa = fmaf(pa, wa, -0.00125372503f);
  pa = fmaf(pa, wa, -0.00417768164f);
  pa = fmaf(pa, wa, 0.246640727f);
  pa = fmaf(pa, wa, 1.50140941f);
  float wb = __builtin_amdgcn_sqrtf(w) - 3.0f;
  float pb = -0.000200214257f;
  pb = fmaf(pb, wb, 0.000100950558f);
  pb = fmaf(pb, wb, 0.00134934322f);
  pb = fmaf(pb, wb, -0.00367342844f);
  pb = fmaf(pb, wb, 0.00573950773f);
  pb = fmaf(pb, wb, -0.0076224613f);
  pb = fmaf(pb, wb, 0.00943887047f);
  pb = fmaf(pb, wb, 1.00167406f);
  pb = fmaf(pb, wb, 2.83297682f);
  float p = (w < 5.0f) ? pa : pb;
  return p * x;
}

// Lean GELU: erf via A&S 7.1.25 (3-term, |err|<=2.5e-5), native v_rcp/v_exp.
__device__ __forceinline__ float gelu_fast(float x) {
  float z  = x * 0.7071067811865475f;
  float az = fabsf(z);
  float t  = __builtin_amdgcn_rcpf(fmaf(0.47047f, az, 1.0f));
  float p  = fmaf(0.7478556f, t, -0.0958798f);
  p = fmaf(p, t, 0.3480242f);
  float e  = __builtin_amdgcn_exp2f(az * az * -1.4426950408889634f);
  float te = t * e;
  float er = fmaf(-p, te, 1.0f);
  er = copysignf(er, z);
  float h = 0.5f * x;
  return fmaf(h, er, h);
}

// Transposed MFMA micro-GEMM: D[m][n] = sum_k W^T[m][k] * h^T[k][n].
// A-frag = packed weights (wave-contiguous 1KB bursts, mtile-major),
// B-frag = activations from LDS row-major [32][BSTRIDE] (h^T[k][n]=h[n][k]).
// 2 mtiles x 2 ntiles per wave; each A/B frag shared by 2 MFMAs.
template<int KSTEPS, int BSTRIDE, int UNROLL>
__device__ __forceinline__ void gemm2t(const bf16* __restrict__ h_lds,
                                       const bf16* __restrict__ A_pk,
                                       int lane, floatx4 (&acc)[2][2]) {
  const int nrow = lane & 15, q = lane >> 4;
  const bf16* b0 = h_lds + nrow * BSTRIDE + q * 8;
  const bf16* a0 = A_pk + lane * 8;
#pragma unroll UNROLL
  for (int ks = 0; ks < KSTEPS; ++ks) {
    bf16x8 bf0 = *(const bf16x8*)(b0 + ks * 32);
    bf16x8 bf1 = *(const bf16x8*)(b0 + 16 * BSTRIDE + ks * 32);
    bf16x8 aA  = *(const bf16x8*)(a0 + ks * 512);
    bf16x8 aB  = *(const bf16x8*)(a0 + (KSTEPS + ks) * 512);
    acc[0][0] = __builtin_amdgcn_mfma_f32_16x16x32_bf16(aA, bf0, acc[0][0], 0, 0, 0);
    acc[0][1] = __builtin_amdgcn_mfma_f32_16x16x32_bf16(aA, bf1, acc[0][1], 0, 0, 0);
    acc[1][0] = __builtin_amdgcn_mfma_f32_16x16x32_bf16(aB, bf0, acc[1][0], 0, 0, 0);
    acc[1][1] = __builtin_amdgcn_mfma_f32_16x16x32_bf16(aB, bf1, acc[1][1], 0, 0, 0);
  }
}

// Layer-4 GEMM: ks0..W4LKS-1 A-frags from the LDS-persisted w4 copy (loaded
// once at init; both ntile groups share it), rest streamed from global.
// unroll 4 (R14: full unroll spills at the 64-reg budget).
template<int BSTRIDE>
__device__ __forceinline__ void gemm1t_l(const bf16* __restrict__ h_lds,
                                         const bf16* __restrict__ A_pk,
                                         const bf16* __restrict__ w4l_mt,
                                         int lane, floatx4& acc) {
  const int nrow = lane & 15, q = lane >> 4;
  const bf16* b0 = h_lds + nrow * BSTRIDE + q * 8;
  const bf16* s0 = w4l_mt + lane * 8;
#pragma unroll 4
  for (int ks = 0; ks < W4LKS; ++ks) {
    bf16x8 bfr = *(const bf16x8*)(b0 + ks * 32);
    bf16x8 af  = *(const bf16x8*)(s0 + ks * 512);
    acc = __builtin_amdgcn_mfma_f32_16x16x32_bf16(af, bfr, acc, 0, 0, 0);
  }
  const bf16* a0 = A_pk + lane * 8;
#pragma unroll 4
  for (int ks = W4LKS; ks < 16; ++ks) {
    bf16x8 bfr = *(const bf16x8*)(b0 + ks * 32);
    bf16x8 af  = *(const bf16x8*)(a0 + ks * 512);
    acc = __builtin_amdgcn_mfma_f32_16x16x32_bf16(af, bfr, acc, 0, 0, 0);
  }
}

// ---------------------------------------------------------------------------
// Prep (unchanged): pack weights bf16 fragment-order; per-step L1 bias; step
// consts; folded keys. Packed index i = ((mt*KS+ks)*64+lane)*8+j maps to
// hidden-col mt*16+(lane&15), k = ks*32+(lane>>4)*8+j.
// ---------------------------------------------------------------------------
__global__ void diff_prep(const float* __restrict__ W1, const float* __restrict__ b1,
                          const float* __restrict__ W2, const float* __restrict__ W3,
                          const float* __restrict__ W4, const int* __restrict__ tsurv,
                          bf16* __restrict__ w1p, bf16* __restrict__ w1cp,
                          bf16* __restrict__ w2p, bf16* __restrict__ w3p,
                          bf16* __restrict__ w4p,
                          float* __restrict__ eb1, uint32_t* __restrict__ fk,
                          float* __restrict__ cst) {
  const int tid = blockIdx.x * blockDim.x + threadIdx.x;
  const int nth = gridDim.x * blockDim.x;
  for (int i = tid; i < 512 * 128; i += nth) {
    int j = i & 7, lane = (i >> 3) & 63, ks = (i >> 9) & 3, ntg = i >> 11;
    int n = ntg * 16 + (lane & 15);
    int k = ks * 32 + (lane >> 4) * 8 + j;
    w1p[i]  = (bf16)W1[k * 512 + n];
    w1cp[i] = (bf16)W1[(128 + k) * 512 + n];
  }
  for (int i = tid; i < 512 * 512; i += nth) {
    int j = i & 7, lane = (i >> 3) & 63, ks = (i >> 9) & 15, ntg = i >> 13;
    int n = ntg * 16 + (lane & 15);
    int k = ks * 32 + (lane >> 4) * 8 + j;
    w2p[i] = (bf16)W2[k * 512 + n];
    w3p[i] = (bf16)W3[k * 512 + n];
  }
  for (int i = tid; i < 128 * 512; i += nth) {
    int j = i & 7, lane = (i >> 3) & 63, ks = (i >> 9) & 15, ntg = i >> 13;
    int n = ntg * 16 + (lane & 15);
    int k = ks * 32 + (lane >> 4) * 8 + j;
    w4p[i] = (bf16)W4[k * 128 + n];
  }
  const float tgt = (tsurv[0] != 0) ? 0.0f : 1.0f;
  for (int i = tid; i < NSTEPS * 512; i += nth) {
    int t = i >> 9, n = i & 511;
    eb1[i] = b1[n] + ((float)t / 50.0f) * W1[256 * 512 + n] + tgt * W1[257 * 512 + n];
  }
  if (tid == 0) {
    float ac = 1.0f;
    for (int t = 0; t < NSTEPS; ++t) {
      float beta  = 1e-4f + (0.02f - 1e-4f) * ((float)t / 49.0f);
      float alpha = 1.0f - beta;
      ac *= alpha;
      cst[t]            = beta / sqrtf(1.0f - ac);
      cst[NSTEPS + t]   = 1.0f / sqrtf(alpha);
      cst[2*NSTEPS + t] = sqrtf(beta);
      uint32_t o0, o1;
      threefry2x32(0u, 42u, 0u, (uint32_t)t, o0, o1);  // fold_in(key(42), t)
      fk[t] = o0; fk[NSTEPS + t] = o1;
    }
  }
}

// ---------------------------------------------------------------------------
// Main persistent kernel: 256 WGs x 1024 threads, 16 waves.
// Layers 1-3 (transposed): wave w owns hidden-cols [w*32,(w+1)*32) x all 32
// batch rows (2 ntiles). Layer 4: mtile4 = w&7 (x-cols), ntile4 = w>>3 (row
// half); w4 ks0-9 served from the per-CU LDS copy (w4l), ks10-15 from L2.
// hbA/hbB double-buffer, 4 barriers/step. LDS 153.5KB (73.5 + 80 w4l).
// ---------------------------------------------------------------------------
__global__ __launch_bounds__(1024, 4) void diff_main(
    const float* __restrict__ cond, const float* __restrict__ xinit,
    const bf16* __restrict__ w1p, const bf16* __restrict__ w1cp,
    const bf16* __restrict__ w2p, const bf16* __restrict__ w3p,
    const bf16* __restrict__ w4p,
    const float* __restrict__ eb1, const float* __restrict__ b2,
    const float* __restrict__ b3, const float* __restrict__ b4,
    const uint32_t* __restrict__ fk, const float* __restrict__ cst,
    float* __restrict__ out) {
  __shared__ bf16 xb[WG_ROWS * XB_STRIDE];
  __shared__ bf16 hbA[WG_ROWS * H_STRIDE];
  __shared__ bf16 hbB[WG_ROWS * H_STRIDE];
  __shared__ bf16 w4l[8 * W4LKS * 512];     // w4 ks0-9, all 8 mtiles (80KB)

  const int tid  = threadIdx.x;
  const int wave = tid >> 6;
  const int lane = tid & 63;
  const int nrow = lane & 15, q = lane >> 4;
  const int r0   = blockIdx.x * WG_ROWS;
  const int mc0  = wave * 32;               // hidden-col slice base (L1-3)
  const int qc   = q * 4;                   // lane's 4-col group within a tile

  const int mtile4 = wave & 7;              // L4: x-col tile
  const int ntile4 = wave >> 3;             // L4: batch-row half
  const int n4     = ntile4 * 16 + nrow;    // L4 lane's batch row (local)
  const int xc0    = mtile4 * 16 + qc;      // L4 lane's first x-col

  // ---- init: stage x_init(bf16)->xb, cond(bf16)->hbA, x-state->regs ----
  {
    const int row = tid >> 5;
    const int c4  = (tid & 31) * 4;
    float4 a = *(const float4*)(xinit + (size_t)(r0 + row) * 128 + c4);
    float4 c = *(const float4*)(cond  + (size_t)(r0 + row) * 128 + c4);
    bf16x4 x4, c4v;
    x4[0] = (bf16)a.x; x4[1] = (bf16)a.y; x4[2] = (bf16)a.z; x4[3] = (bf16)a.w;
    c4v[0] = (bf16)c.x; c4v[1] = (bf16)c.y; c4v[2] = (bf16)c.z; c4v[3] = (bf16)c.w;
    *(bf16x4*)(xb  + row * XB_STRIDE + c4) = x4;
    *(bf16x4*)(hbA + row * H_STRIDE  + c4) = c4v;
  }
  // ---- one-time w4 ks0..W4LKS-1 -> LDS. Dest vec8 i = mt*(W4LKS*64)+rem
  // maps to src vec8 mt*1024+rem (src keeps all 16 ks = 1024 vec8/mt). ----
  for (int i = tid; i < 8 * W4LKS * 64; i += 1024) {
    const int mt = i / (W4LKS * 64), rem = i % (W4LKS * 64);
    ((bf16x8*)w4l)[i] = ((const bf16x8*)w4p)[mt * 1024 + rem];
  }
  float4 xreg = *(const float4*)(xinit + (size_t)(r0 + n4) * 128 + xc0);
  __syncthreads();

  // ---- cproj = (cond @ W1[128:256,:])^T — acc layout matches layer 1 ----
  floatx4 cpr[2][2] = {};
  gemm2t<4, H_STRIDE, 4>(hbA, w1cp + (wave * 2) * 4 * 512, lane, cpr);
  __syncthreads();  // cond reads done; hbA free

  for (int t = NSTEPS - 1; t >= 0; --t) {
    // ---- layer 1: hbA = gelu(x@W1[:128] + cproj + eb1[t]) (transposed) ----
    {
      floatx4 acc[2][2] = {};
      gemm2t<4, XB_STRIDE, 4>(xb, w1p + (wave * 2) * 4 * 512, lane, acc);
      const float* ebt = eb1 + t * 512;
#pragma unroll
      for (int mt = 0; mt < 2; ++mt) {
        const int col = mc0 + mt * 16 + qc;
        float4 bb = *(const float4*)(ebt + col);
#pragma unroll
        for (int nt = 0; nt < 2; ++nt) {
          bf16x4 g;
#pragma unroll
          for (int r = 0; r < 4; ++r)
            g[r] = (bf16)gelu_fast(acc[mt][nt][r] + cpr[mt][nt][r] + ((const float*)&bb)[r]);
          *(bf16x4*)(hbA + (nt * 16 + nrow) * H_STRIDE + col) = g;
        }
      }
    }
    __syncthreads();  // B1

    // ---- layer 2: hbB = gelu(hbA@W2 + b2) ----
    {
      floatx4 acc[2][2] = {};
      gemm2t<16, H_STRIDE, 4>(hbA, w2p + (wave * 2) * 16 * 512, lane, acc);
#pragma unroll
      for (int mt = 0; mt < 2; ++mt) {
        const int col = mc0 + mt * 16 + qc;
        float4 bb = *(const float4*)(b2 + col);
#pragma unroll
        for (int nt = 0; nt < 2; ++nt) {
          bf16x4 g;
#pragma unroll
          for (int r = 0; r < 4; ++r)
            g[r] = (bf16)gelu_fast(acc[mt][nt][r] + ((const float*)&bb)[r]);
          *(bf16x4*)(hbB + (nt * 16 + nrow) * H_STRIDE + col) = g;
        }
      }
    }
    __syncthreads();  // B2

    // ---- layer 3: hbA = gelu(hbB@W3 + b3) ----
    {
      floatx4 acc[2][2] = {};
      gemm2t<16, H_STRIDE, 4>(hbB, w3p + (wave * 2) * 16 * 512, lane, acc);
#pragma unroll
      for (int mt = 0; mt < 2; ++mt) {
        const int col = mc0 + mt * 16 + qc;
        float4 bb = *(const float4*)(b3 + col);
#pragma unroll
        for (int nt = 0; nt < 2; ++nt) {
          bf16x4 g;
#pragma unroll
          for (int r = 0; r < 4; ++r)
            g[r] = (bf16)gelu_fast(acc[mt][nt][r] + ((const float*)&bb)[r]);
          *(bf16x4*)(hbA + (nt * 16 + nrow) * H_STRIDE + col) = g;
        }
      }
    }
    __syncthreads();  // B3

    // ---- layer 4 + DDPM update: lane owns 4 consecutive x-cols, 1 row.
    // A ks0-9 from LDS (w4l), ks10-15 from L2. Branchless noise. ----
    {
      floatx4 acc = {};
      gemm1t_l<H_STRIDE>(hbA + ntile4 * 16 * H_STRIDE,
                         w4p + mtile4 * 16 * 512,
                         w4l + mtile4 * W4LKS * 512, lane, acc);
      const float c1 = cst[t], c2 = cst[NSTEPS + t], c3 = cst[2 * NSTEPS + t];
      const uint32_t fk0 = fk[t], fk1 = fk[NSTEPS + t];
      const float zscale = (t > 0) ? 1.4142135381698608f * c3 : 0.0f;
      float4 bb = *(const float4*)(b4 + xc0);
      const uint32_t gbase = (uint32_t)(r0 + n4) * 128u + (uint32_t)xc0;
      bf16x4 xpk;
#pragma unroll
      for (int r = 0; r < 4; ++r) {
        float np = acc[r] + ((const float*)&bb)[r];
        uint32_t o0, o1;
        threefry2x32(fk0, fk1, 0u, gbase + (uint32_t)r, o0, o1);
        uint32_t bits = o0 ^ o1;
        float f01 = __uint_as_float((bits >> 9) | 0x3F800000u) - 1.0f;
        float u = fmaxf(-0.99999994f, fmaf(f01, 2.0f, -0.99999994f));
        float z = zscale * erfinv_xla_bl(u);
        float xn = (((float*)&xreg)[r] - c1 * np) * c2 + z;
        ((float*)&xreg)[r] = xn;
        xpk[r] = (bf16)xn;
      }
      *(bf16x4*)(xb + n4 * XB_STRIDE + xc0) = xpk;
    }
    __syncthreads();  // B4
  }

  // ---- writeout: 4 consecutive floats per lane ----
  *(float4*)(out + (size_t)(r0 + n4) * 128 + xc0) = xreg;
}

// ---------------------------------------------------------------------------
extern "C" void kernel_launch(void* const* d_in, const int* in_sizes, int n_in,
                              void* d_out, int out_size, void* d_ws, size_t ws_size,
                              hipStream_t stream) {
  const float* cond  = (const float*)d_in[0];
  const float* xinit = (const float*)d_in[1];
  const float* W1 = (const float*)d_in[2];
  const float* b1 = (const float*)d_in[3];
  const float* W2 = (const float*)d_in[4];
  const float* b2 = (const float*)d_in[5];
  const float* W3 = (const float*)d_in[6];
  const float* b3 = (const float*)d_in[7];
  const float* W4 = (const float*)d_in[8];
  const float* b4 = (const float*)d_in[9];
  const int* tsurv = (const int*)d_in[10];

  char* ws = (char*)d_ws;
  bf16* w1p  = (bf16*)(ws + 0);              // 512*128*2 = 131072
  bf16* w1cp = (bf16*)(ws + 131072);         // 131072
  bf16* w2p  = (bf16*)(ws + 262144);         // 512*512*2 = 524288
  bf16* w3p  = (bf16*)(ws + 786432);         // 524288
  bf16* w4p  = (bf16*)(ws + 1310720);        // 128*512*2 = 131072
  float* eb1 = (float*)(ws + 1441792);       // 50*512*4 = 102400
  uint32_t* fkp = (uint32_t*)(ws + 1544192); // 100*4
  float* cstp = (float*)(ws + 1544704);      // 150*4

  diff_prep<<<1024, 256, 0, stream>>>(W1, b1, W2, W3, W4, tsurv,
                                      w1p, w1cp, w2p, w3p, w4p, eb1, fkp, cstp);
  diff_main<<<256, 1024, 0, stream>>>(cond, xinit, w1p, w1cp, w2p, w3p, w4p,
                                      eb1, b2, b3, b4, fkp, cstp, (float*)d_out);
}

// Round 14
// 937.967 us; speedup vs baseline: 1.3596x; 1.3596x over previous
//
#include <hip/hip_runtime.h>
#include <stdint.h>
#include <stddef.h>

// ---------------------------------------------------------------------------
// CounterfactualDiffusion: 50 sequential steps of 4-layer MLP (258->512->512
// ->512->128) + DDPM update with JAX partitionable-threefry noise, batch 8192.
// Persistent kernel: 256 WGs x 1024 threads (16 waves), each WG owns 32 rows.
// R6/R11/R15 (985us, clean): transposed dataflow (W = MFMA A-operand, h^T=B).
// R17 (969.5us, session best, clean: FETCH 11.3MB / WRITE 6MB / VGPR 64):
// persist w4 ks0-7 in LDS once -> -128KB/CU/step L2 stream. Measured stream
// sensitivity ~0.125us per KB/step removed.
// R18 FAILED (1275us): W4LKS 8->10 changed gemm trip counts to 10/6 (non-
// unroll-aligned) -> codegen spill (WRITE 32MB) -> scratch thrashed L2 ->
// entire weight set re-fetched from HBM every step (FETCH 519MB). Lesson:
// at the 64-reg wall, only power-of-2 / unroll-aligned loop shapes are
// codegen-stable.
// Exhausted/ruled out: register prefetch (7 spills), TLP (R12), VALU count
// (R15: zero), bank conflicts (2-way writes, free), 2 WGs/CU (R16), full
// unroll (R14), W4LKS>8 (R18). R19: exact R17 revert — plateau candidate.
// ---------------------------------------------------------------------------

typedef __bf16 bf16;
typedef __bf16 bf16x4 __attribute__((ext_vector_type(4)));
typedef __bf16 bf16x8 __attribute__((ext_vector_type(8)));
typedef float  floatx4 __attribute__((ext_vector_type(4)));

#define NSTEPS    50
#define WG_ROWS   32
#define XB_STRIDE 136   // 128 + 8 pad
#define H_STRIDE  520   // 512 + 8 pad
#define W4LKS     8     // w4 K-steps persisted in LDS (of 16) — 8 is the
                        // codegen-stable maximum (R18: 10 spills)

__device__ __forceinline__ uint32_t rotl32(uint32_t x, int r) {
  return (x << r) | (x >> (32 - r));
}

// JAX threefry-2x32, 20 rounds.
__device__ __forceinline__ void threefry2x32(uint32_t k0, uint32_t k1,
                                             uint32_t x0, uint32_t x1,
                                             uint32_t& o0, uint32_t& o1) {
  uint32_t k2 = k0 ^ k1 ^ 0x1BD11BDAu;
  x0 += k0; x1 += k1;
#define TF_R(R) { x0 += x1; x1 = rotl32(x1, R); x1 ^= x0; }
  TF_R(13) TF_R(15) TF_R(26) TF_R(6)
  x0 += k1; x1 += k2 + 1u;
  TF_R(17) TF_R(29) TF_R(16) TF_R(24)
  x0 += k2; x1 += k0 + 2u;
  TF_R(13) TF_R(15) TF_R(26) TF_R(6)
  x0 += k0; x1 += k1 + 3u;
  TF_R(17) TF_R(29) TF_R(16) TF_R(24)
  x0 += k1; x1 += k2 + 4u;
  TF_R(13) TF_R(15) TF_R(26) TF_R(6)
  x0 += k2; x1 += k0 + 5u;
#undef TF_R
  o0 = x0; o1 = x1;
}

// XLA's ErfInv32 (Giles), branchless select: both polys computed, vcc select.
__device__ __forceinline__ float erfinv_xla_bl(float x) {
  float w = -0.6931471805599453f * __builtin_amdgcn_logf(fmaf(-x, x, 1.0f));
  float wa = w - 2.5f;
  float pa = 2.81022636e-08f;
  pa = fmaf(pa, wa, 3.43273939e-07f);
  pa = fmaf(pa, wa, -3.5233877e-06f);
  pa = fmaf(pa, wa, -4.39150654e-06f);
  pa = fmaf(pa, wa, 0.00021858087f);
  pa = fmaf(pa, wa, -0.00125372503f);
  pa = fmaf(pa, wa, -0.00417768164f);
  pa = fmaf(pa, wa, 0.246640727f);
  pa = fmaf(pa, wa, 1.50140941f);
  float wb = __builtin_amdgcn_sqrtf(w) - 3.0f;
  float pb = -0.000200214257f;
  pb = fmaf(pb, wb, 0.000100950558f);
  pb = fmaf(pb, wb, 0.00134934322f);
  pb = fmaf(pb, wb, -0.00367342844f);
  pb = fmaf(pb, wb, 0.00573950773f);
  pb = fmaf(pb, wb, -0.0076224613f);
  pb = fmaf(pb, wb, 0.00943887047f);
  pb = fmaf(pb, wb, 1.00167406f);
  pb = fmaf(pb, wb, 2.83297682f);
  float p = (w < 5.0f) ? pa : pb;
  return p * x;
}

// Lean GELU: erf via A&S 7.1.25 (3-term, |err|<=2.5e-5), native v_rcp/v_exp.
__device__ __forceinline__ float gelu_fast(float x) {
  float z  = x * 0.7071067811865475f;
  float az = fabsf(z);
  float t  = __builtin_amdgcn_rcpf(fmaf(0.47047f, az, 1.0f));
  float p  = fmaf(0.7478556f, t, -0.0958798f);
  p = fmaf(p, t, 0.3480242f);
  float e  = __builtin_amdgcn_exp2f(az * az * -1.4426950408889634f);
  float te = t * e;
  float er = fmaf(-p, te, 1.0f);
  er = copysignf(er, z);
  float h = 0.5f * x;
  return fmaf(h, er, h);
}

// Transposed MFMA micro-GEMM: D[m][n] = sum_k W^T[m][k] * h^T[k][n].
// A-frag = packed weights (wave-contiguous 1KB bursts, mtile-major),
// B-frag = activations from LDS row-major [32][BSTRIDE] (h^T[k][n]=h[n][k]).
// 2 mtiles x 2 ntiles per wave; each A/B frag shared by 2 MFMAs.
template<int KSTEPS, int BSTRIDE, int UNROLL>
__device__ __forceinline__ void gemm2t(const bf16* __restrict__ h_lds,
                                       const bf16* __restrict__ A_pk,
                                       int lane, floatx4 (&acc)[2][2]) {
  const int nrow = lane & 15, q = lane >> 4;
  const bf16* b0 = h_lds + nrow * BSTRIDE + q * 8;
  const bf16* a0 = A_pk + lane * 8;
#pragma unroll UNROLL
  for (int ks = 0; ks < KSTEPS; ++ks) {
    bf16x8 bf0 = *(const bf16x8*)(b0 + ks * 32);
    bf16x8 bf1 = *(const bf16x8*)(b0 + 16 * BSTRIDE + ks * 32);
    bf16x8 aA  = *(const bf16x8*)(a0 + ks * 512);
    bf16x8 aB  = *(const bf16x8*)(a0 + (KSTEPS + ks) * 512);
    acc[0][0] = __builtin_amdgcn_mfma_f32_16x16x32_bf16(aA, bf0, acc[0][0], 0, 0, 0);
    acc[0][1] = __builtin_amdgcn_mfma_f32_16x16x32_bf16(aA, bf1, acc[0][1], 0, 0, 0);
    acc[1][0] = __builtin_amdgcn_mfma_f32_16x16x32_bf16(aB, bf0, acc[1][0], 0, 0, 0);
    acc[1][1] = __builtin_amdgcn_mfma_f32_16x16x32_bf16(aB, bf1, acc[1][1], 0, 0, 0);
  }
}

// Layer-4 GEMM: ks0..W4LKS-1 A-frags from the LDS-persisted w4 copy (loaded
// once at init; both ntile groups share it), rest streamed from global.
// unroll 4 (R14: full unroll spills at the 64-reg budget).
template<int BSTRIDE>
__device__ __forceinline__ void gemm1t_l(const bf16* __restrict__ h_lds,
                                         const bf16* __restrict__ A_pk,
                                         const bf16* __restrict__ w4l_mt,
                                         int lane, floatx4& acc) {
  const int nrow = lane & 15, q = lane >> 4;
  const bf16* b0 = h_lds + nrow * BSTRIDE + q * 8;
  const bf16* s0 = w4l_mt + lane * 8;
#pragma unroll 4
  for (int ks = 0; ks < W4LKS; ++ks) {
    bf16x8 bfr = *(const bf16x8*)(b0 + ks * 32);
    bf16x8 af  = *(const bf16x8*)(s0 + ks * 512);
    acc = __builtin_amdgcn_mfma_f32_16x16x32_bf16(af, bfr, acc, 0, 0, 0);
  }
  const bf16* a0 = A_pk + lane * 8;
#pragma unroll 4
  for (int ks = W4LKS; ks < 16; ++ks) {
    bf16x8 bfr = *(const bf16x8*)(b0 + ks * 32);
    bf16x8 af  = *(const bf16x8*)(a0 + ks * 512);
    acc = __builtin_amdgcn_mfma_f32_16x16x32_bf16(af, bfr, acc, 0, 0, 0);
  }
}

// ---------------------------------------------------------------------------
// Prep (unchanged): pack weights bf16 fragment-order; per-step L1 bias; step
// consts; folded keys. Packed index i = ((mt*KS+ks)*64+lane)*8+j maps to
// hidden-col mt*16+(lane&15), k = ks*32+(lane>>4)*8+j.
// ---------------------------------------------------------------------------
__global__ void diff_prep(const float* __restrict__ W1, const float* __restrict__ b1,
                          const float* __restrict__ W2, const float* __restrict__ W3,
                          const float* __restrict__ W4, const int* __restrict__ tsurv,
                          bf16* __restrict__ w1p, bf16* __restrict__ w1cp,
                          bf16* __restrict__ w2p, bf16* __restrict__ w3p,
                          bf16* __restrict__ w4p,
                          float* __restrict__ eb1, uint32_t* __restrict__ fk,
                          float* __restrict__ cst) {
  const int tid = blockIdx.x * blockDim.x + threadIdx.x;
  const int nth = gridDim.x * blockDim.x;
  for (int i = tid; i < 512 * 128; i += nth) {
    int j = i & 7, lane = (i >> 3) & 63, ks = (i >> 9) & 3, ntg = i >> 11;
    int n = ntg * 16 + (lane & 15);
    int k = ks * 32 + (lane >> 4) * 8 + j;
    w1p[i]  = (bf16)W1[k * 512 + n];
    w1cp[i] = (bf16)W1[(128 + k) * 512 + n];
  }
  for (int i = tid; i < 512 * 512; i += nth) {
    int j = i & 7, lane = (i >> 3) & 63, ks = (i >> 9) & 15, ntg = i >> 13;
    int n = ntg * 16 + (lane & 15);
    int k = ks * 32 + (lane >> 4) * 8 + j;
    w2p[i] = (bf16)W2[k * 512 + n];
    w3p[i] = (bf16)W3[k * 512 + n];
  }
  for (int i = tid; i < 128 * 512; i += nth) {
    int j = i & 7, lane = (i >> 3) & 63, ks = (i >> 9) & 15, ntg = i >> 13;
    int n = ntg * 16 + (lane & 15);
    int k = ks * 32 + (lane >> 4) * 8 + j;
    w4p[i] = (bf16)W4[k * 128 + n];
  }
  const float tgt = (tsurv[0] != 0) ? 0.0f : 1.0f;
  for (int i = tid; i < NSTEPS * 512; i += nth) {
    int t = i >> 9, n = i & 511;
    eb1[i] = b1[n] + ((float)t / 50.0f) * W1[256 * 512 + n] + tgt * W1[257 * 512 + n];
  }
  if (tid == 0) {
    float ac = 1.0f;
    for (int t = 0; t < NSTEPS; ++t) {
      float beta  = 1e-4f + (0.02f - 1e-4f) * ((float)t / 49.0f);
      float alpha = 1.0f - beta;
      ac *= alpha;
      cst[t]            = beta / sqrtf(1.0f - ac);
      cst[NSTEPS + t]   = 1.0f / sqrtf(alpha);
      cst[2*NSTEPS + t] = sqrtf(beta);
      uint32_t o0, o1;
      threefry2x32(0u, 42u, 0u, (uint32_t)t, o0, o1);  // fold_in(key(42), t)
      fk[t] = o0; fk[NSTEPS + t] = o1;
    }
  }
}

// ---------------------------------------------------------------------------
// Main persistent kernel: 256 WGs x 1024 threads, 16 waves.
// Layers 1-3 (transposed): wave w owns hidden-cols [w*32,(w+1)*32) x all 32
// batch rows (2 ntiles). Layer 4: mtile4 = w&7 (x-cols), ntile4 = w>>3 (row
// half); w4 ks0-7 served from the per-CU LDS copy (w4l), ks8-15 from L2.
// hbA/hbB double-buffer, 4 barriers/step. LDS 137.5KB (73.5 + 64 w4l).
// ---------------------------------------------------------------------------
__global__ __launch_bounds__(1024, 4) void diff_main(
    const float* __restrict__ cond, const float* __restrict__ xinit,
    const bf16* __restrict__ w1p, const bf16* __restrict__ w1cp,
    const bf16* __restrict__ w2p, const bf16* __restrict__ w3p,
    const bf16* __restrict__ w4p,
    const float* __restrict__ eb1, const float* __restrict__ b2,
    const float* __restrict__ b3, const float* __restrict__ b4,
    const uint32_t* __restrict__ fk, const float* __restrict__ cst,
    float* __restrict__ out) {
  __shared__ bf16 xb[WG_ROWS * XB_STRIDE];
  __shared__ bf16 hbA[WG_ROWS * H_STRIDE];
  __shared__ bf16 hbB[WG_ROWS * H_STRIDE];
  __shared__ bf16 w4l[8 * W4LKS * 512];     // w4 ks0-7, all 8 mtiles (64KB)

  const int tid  = threadIdx.x;
  const int wave = tid >> 6;
  const int lane = tid & 63;
  const int nrow = lane & 15, q = lane >> 4;
  const int r0   = blockIdx.x * WG_ROWS;
  const int mc0  = wave * 32;               // hidden-col slice base (L1-3)
  const int qc   = q * 4;                   // lane's 4-col group within a tile

  const int mtile4 = wave & 7;              // L4: x-col tile
  const int ntile4 = wave >> 3;             // L4: batch-row half
  const int n4     = ntile4 * 16 + nrow;    // L4 lane's batch row (local)
  const int xc0    = mtile4 * 16 + qc;      // L4 lane's first x-col

  // ---- init: stage x_init(bf16)->xb, cond(bf16)->hbA, x-state->regs ----
  {
    const int row = tid >> 5;
    const int c4  = (tid & 31) * 4;
    float4 a = *(const float4*)(xinit + (size_t)(r0 + row) * 128 + c4);
    float4 c = *(const float4*)(cond  + (size_t)(r0 + row) * 128 + c4);
    bf16x4 x4, c4v;
    x4[0] = (bf16)a.x; x4[1] = (bf16)a.y; x4[2] = (bf16)a.z; x4[3] = (bf16)a.w;
    c4v[0] = (bf16)c.x; c4v[1] = (bf16)c.y; c4v[2] = (bf16)c.z; c4v[3] = (bf16)c.w;
    *(bf16x4*)(xb  + row * XB_STRIDE + c4) = x4;
    *(bf16x4*)(hbA + row * H_STRIDE  + c4) = c4v;
  }
  // ---- one-time w4 ks0-7 -> LDS (dest vec8 i = mt*512+rem maps to src
  // vec8 mt*1024+rem, since src has 16 ks and dest keeps 8) ----
  for (int i = tid; i < 4096; i += 1024) {
    const int mt = i >> 9, rem = i & 511;
    ((bf16x8*)w4l)[i] = ((const bf16x8*)w4p)[(mt << 10) + rem];
  }
  float4 xreg = *(const float4*)(xinit + (size_t)(r0 + n4) * 128 + xc0);
  __syncthreads();

  // ---- cproj = (cond @ W1[128:256,:])^T — acc layout matches layer 1 ----
  floatx4 cpr[2][2] = {};
  gemm2t<4, H_STRIDE, 4>(hbA, w1cp + (wave * 2) * 4 * 512, lane, cpr);
  __syncthreads();  // cond reads done; hbA free

  for (int t = NSTEPS - 1; t >= 0; --t) {
    // ---- layer 1: hbA = gelu(x@W1[:128] + cproj + eb1[t]) (transposed) ----
    {
      floatx4 acc[2][2] = {};
      gemm2t<4, XB_STRIDE, 4>(xb, w1p + (wave * 2) * 4 * 512, lane, acc);
      const float* ebt = eb1 + t * 512;
#pragma unroll
      for (int mt = 0; mt < 2; ++mt) {
        const int col = mc0 + mt * 16 + qc;
        float4 bb = *(const float4*)(ebt + col);
#pragma unroll
        for (int nt = 0; nt < 2; ++nt) {
          bf16x4 g;
#pragma unroll
          for (int r = 0; r < 4; ++r)
            g[r] = (bf16)gelu_fast(acc[mt][nt][r] + cpr[mt][nt][r] + ((const float*)&bb)[r]);
          *(bf16x4*)(hbA + (nt * 16 + nrow) * H_STRIDE + col) = g;
        }
      }
    }
    __syncthreads();  // B1

    // ---- layer 2: hbB = gelu(hbA@W2 + b2) ----
    {
      floatx4 acc[2][2] = {};
      gemm2t<16, H_STRIDE, 4>(hbA, w2p + (wave * 2) * 16 * 512, lane, acc);
#pragma unroll
      for (int mt = 0; mt < 2; ++mt) {
        const int col = mc0 + mt * 16 + qc;
        float4 bb = *(const float4*)(b2 + col);
#pragma unroll
        for (int nt = 0; nt < 2; ++nt) {
          bf16x4 g;
#pragma unroll
          for (int r = 0; r < 4; ++r)
            g[r] = (bf16)gelu_fast(acc[mt][nt][r] + ((const float*)&bb)[r]);
          *(bf16x4*)(hbB + (nt * 16 + nrow) * H_STRIDE + col) = g;
        }
      }
    }
    __syncthreads();  // B2

    // ---- layer 3: hbA = gelu(hbB@W3 + b3) ----
    {
      floatx4 acc[2][2] = {};
      gemm2t<16, H_STRIDE, 4>(hbB, w3p + (wave * 2) * 16 * 512, lane, acc);
#pragma unroll
      for (int mt = 0; mt < 2; ++mt) {
        const int col = mc0 + mt * 16 + qc;
        float4 bb = *(const float4*)(b3 + col);
#pragma unroll
        for (int nt = 0; nt < 2; ++nt) {
          bf16x4 g;
#pragma unroll
          for (int r = 0; r < 4; ++r)
            g[r] = (bf16)gelu_fast(acc[mt][nt][r] + ((const float*)&bb)[r]);
          *(bf16x4*)(hbA + (nt * 16 + nrow) * H_STRIDE + col) = g;
        }
      }
    }
    __syncthreads();  // B3

    // ---- layer 4 + DDPM update: lane owns 4 consecutive x-cols, 1 row.
    // A ks0-7 from LDS (w4l), ks8-15 from L2. Branchless noise. ----
    {
      floatx4 acc = {};
      gemm1t_l<H_STRIDE>(hbA + ntile4 * 16 * H_STRIDE,
                         w4p + mtile4 * 16 * 512,
                         w4l + mtile4 * W4LKS * 512, lane, acc);
      const float c1 = cst[t], c2 = cst[NSTEPS + t], c3 = cst[2 * NSTEPS + t];
      const uint32_t fk0 = fk[t], fk1 = fk[NSTEPS + t];
      const float zscale = (t > 0) ? 1.4142135381698608f * c3 : 0.0f;
      float4 bb = *(const float4*)(b4 + xc0);
      const uint32_t gbase = (uint32_t)(r0 + n4) * 128u + (uint32_t)xc0;
      bf16x4 xpk;
#pragma unroll
      for (int r = 0; r < 4; ++r) {
        float np = acc[r] + ((const float*)&bb)[r];
        uint32_t o0, o1;
        threefry2x32(fk0, fk1, 0u, gbase + (uint32_t)r, o0, o1);
        uint32_t bits = o0 ^ o1;
        float f01 = __uint_as_float((bits >> 9) | 0x3F800000u) - 1.0f;
        float u = fmaxf(-0.99999994f, fmaf(f01, 2.0f, -0.99999994f));
        float z = zscale * erfinv_xla_bl(u);
        float xn = (((float*)&xreg)[r] - c1 * np) * c2 + z;
        ((float*)&xreg)[r] = xn;
        xpk[r] = (bf16)xn;
      }
      *(bf16x4*)(xb + n4 * XB_STRIDE + xc0) = xpk;
    }
    __syncthreads();  // B4
  }

  // ---- writeout: 4 consecutive floats per lane ----
  *(float4*)(out + (size_t)(r0 + n4) * 128 + xc0) = xreg;
}

// ---------------------------------------------------------------------------
extern "C" void kernel_launch(void* const* d_in, const int* in_sizes, int n_in,
                              void* d_out, int out_size, void* d_ws, size_t ws_size,
                              hipStream_t stream) {
  const float* cond  = (const float*)d_in[0];
  const float* xinit = (const float*)d_in[1];
  const float* W1 = (const float*)d_in[2];
  const float* b1 = (const float*)d_in[3];
  const float* W2 = (const float*)d_in[4];
  const float* b2 = (const float*)d_in[5];
  const float* W3 = (const float*)d_in[6];
  const float* b3 = (const float*)d_in[7];
  const float* W4 = (const float*)d_in[8];
  const float* b4 = (const float*)d_in[9];
  const int* tsurv = (const int*)d_in[10];

  char* ws = (char*)d_ws;
  bf16* w1p  = (bf16*)(ws + 0);              // 512*128*2 = 131072
  bf16* w1cp = (bf16*)(ws + 131072);         // 131072
  bf16* w2p  = (bf16*)(ws + 262144);         // 512*512*2 = 524288
  bf16* w3p  = (bf16*)(ws + 786432);         // 524288
  bf16* w4p  = (bf16*)(ws + 1310720);        // 128*512*2 = 131072
  float* eb1 = (float*)(ws + 1441792);       // 50*512*4 = 102400
  uint32_t* fkp = (uint32_t*)(ws + 1544192); // 100*4
  float* cstp = (float*)(ws + 1544704);      // 150*4

  diff_prep<<<1024, 256, 0, stream>>>(W1, b1, W2, W3, W4, tsurv,
                                      w1p, w1cp, w2p, w3p, w4p, eb1, fkp, cstp);
  diff_main<<<256, 1024, 0, stream>>>(cond, xinit, w1p, w1cp, w2p, w3p, w4p,
                                      eb1, b2, b3, b4, fkp, cstp, (float*)d_out);
}